// Round 11
// baseline (433.925 us; speedup 1.0000x reference)
//
#include <hip/hip_runtime.h>
#include <hip/hip_bf16.h>
#include <math.h>

#define BB   4
#define SS   1024
#define DDIM 1024
#define HH   16
#define DKK  64
#define DFFF 4096
#define JC2  64      // K/V j-chunk per LDS stage (attention)

typedef __attribute__((ext_vector_type(8))) short short8;
typedef __attribute__((ext_vector_type(4))) float f32x4;
typedef unsigned short ushort;

__device__ __forceinline__ ushort f2bf(float f) {   // RNE fp32->bf16
    unsigned int u = __float_as_uint(f);
    unsigned int r = (u + 0x7FFFu + ((u >> 16) & 1u)) >> 16;
    return (ushort)r;
}
__device__ __forceinline__ short8 pack8(float4 f0, float4 f1) {
    short8 s;
    s[0] = (short)f2bf(f0.x); s[1] = (short)f2bf(f0.y);
    s[2] = (short)f2bf(f0.z); s[3] = (short)f2bf(f0.w);
    s[4] = (short)f2bf(f1.x); s[5] = (short)f2bf(f1.y);
    s[6] = (short)f2bf(f1.z); s[7] = (short)f2bf(f1.w);
    return s;
}

// async global->LDS, 16B per lane; LDS dest = wave-uniform base + lane*16
#define GLD16(g, l) __builtin_amdgcn_global_load_lds( \
    (const __attribute__((address_space(1))) unsigned int*)(g), \
    (__attribute__((address_space(3))) unsigned int*)(l), 16, 0, 0)

// exp2 via raw v_exp_f32 (base-2 hardware transcendental)
__device__ __forceinline__ float fexp2(float x) { return __builtin_amdgcn_exp2f(x); }

// inclusive 16-lane prefix sum via DPP row_shr (4 VALU ops, no LDS pipe).
__device__ __forceinline__ float scan16(float x) {
    x += __int_as_float(__builtin_amdgcn_update_dpp(0, __float_as_int(x), 0x111, 0xF, 0xF, true));
    x += __int_as_float(__builtin_amdgcn_update_dpp(0, __float_as_int(x), 0x112, 0xF, 0xF, true));
    x += __int_as_float(__builtin_amdgcn_update_dpp(0, __float_as_int(x), 0x114, 0xF, 0xF, true));
    x += __int_as_float(__builtin_amdgcn_update_dpp(0, __float_as_int(x), 0x118, 0xF, 0xF, true));
    return x;
}
// broadcast lane 15 of each 16-group: ds_swizzle bit-mode, and=0x10 or=0x0F xor=0
__device__ __forceinline__ float bcast15(float x) {
    return __int_as_float(__builtin_amdgcn_ds_swizzle(__float_as_int(x), 0x1F0));
}

// ---------- block reductions (256 threads = 4 waves of 64) ----------
__device__ __forceinline__ float block_reduce_sum(float v, float* red, int tid) {
#pragma unroll
    for (int off = 32; off; off >>= 1) v += __shfl_xor(v, off);
    __syncthreads();
    if ((tid & 63) == 0) red[tid >> 6] = v;
    __syncthreads();
    return red[0] + red[1] + red[2] + red[3];
}

// ---------- fp32 -> bf16 convert (Wq/Wk/Wv only; Wo/W1/W2 ride in QKV) ------
struct CvtArgs { const float* s[3]; ushort* d[3]; };
__global__ __launch_bounds__(256) void convert_bf(CvtArgs a) {
    const int seg = blockIdx.y;
    size_t idx = ((size_t)blockIdx.x * 256 + threadIdx.x) * 8;
    const float* s = a.s[seg];
    float4 f0 = *(const float4*)(s + idx);
    float4 f1 = *(const float4*)(s + idx + 4);
    *(short8*)(a.d[seg] + idx) = pack8(f0, f1);
}

// ---------- bf16 MFMA GEMM core (m97-style): C = act(A @ W^T [+ b]) ---------
// CVTA: A is fp32, converted to bf16 during LDS staging.
template <int BM, typename TC, bool RELU, bool BIAS, bool CVTA>
__device__ __forceinline__ void gemm_core(const void* __restrict__ Av, int lda,
                                          const ushort* __restrict__ Bm, int ldb,
                                          const float* __restrict__ bias,
                                          TC* __restrict__ C, int N, int Klen,
                                          int bm, int bn) {
    constexpr int MT = BM / 32;           // m-frags per wave
    constexpr int PA = BM / 32;           // A staging iters per wave
    __shared__ ushort A_s[BM * 64];
    __shared__ ushort B_s[128 * 64];
    const int t = threadIdx.x;
    const int lane = t & 63, w = t >> 6;
    const int wr = w >> 1, wc = w & 1;
    const int fm = lane & 15, fq = lane >> 4;
    const int srl = lane >> 3;            // staging row-in-group
    const int sg8 = ((lane & 7) ^ srl) << 3;   // swizzled global k offset

    f32x4 acc[MT][4];
#pragma unroll
    for (int mt = 0; mt < MT; mt++)
#pragma unroll
        for (int nt = 0; nt < 4; nt++) acc[mt][nt] = (f32x4){0.f, 0.f, 0.f, 0.f};

    for (int kt = 0; kt < Klen; kt += 64) {
        __syncthreads();
        if constexpr (CVTA) {
            const float* Af = (const float*)Av;
#pragma unroll
            for (int p = 0; p < PA; ++p) {
                int rowg = (w * PA + p) * 8;
                const float* src = Af + (size_t)(bm + rowg + srl) * lda + kt + sg8;
                float4 f0 = *(const float4*)(src);
                float4 f1 = *(const float4*)(src + 4);
                *(short8*)&A_s[(rowg + srl) * 64 + ((lane & 7) << 3)] = pack8(f0, f1);
            }
        } else {
            const ushort* A = (const ushort*)Av;
#pragma unroll
            for (int p = 0; p < PA; ++p) {
                int rowg = (w * PA + p) * 8;
                GLD16(A + (size_t)(bm + rowg + srl) * lda + kt + sg8, &A_s[rowg * 64]);
            }
        }
#pragma unroll
        for (int p = 0; p < 4; ++p) {
            int rowg = (w * 4 + p) * 8;
            GLD16(Bm + (size_t)(bn + rowg + srl) * ldb + kt + sg8, &B_s[rowg * 64]);
        }
        __syncthreads();                  // drains vmcnt + lgkmcnt

        short8 av[2][MT], bv[2][4];
        const int sw = fm & 7;
#pragma unroll
        for (int mt = 0; mt < MT; ++mt) {
            int row = wr * (BM / 2) + mt * 16 + fm;
#pragma unroll
            for (int ks = 0; ks < 2; ++ks)
                av[ks][mt] = *(const short8*)&A_s[row * 64 + (((ks * 4 + fq) ^ sw) << 3)];
        }
#pragma unroll
        for (int nt = 0; nt < 4; ++nt) {
            int row = wc * 64 + nt * 16 + fm;
#pragma unroll
            for (int ks = 0; ks < 2; ++ks)
                bv[ks][nt] = *(const short8*)&B_s[row * 64 + (((ks * 4 + fq) ^ sw) << 3)];
        }
#pragma unroll
        for (int ks = 0; ks < 2; ++ks)
#pragma unroll
            for (int mt = 0; mt < MT; ++mt)
#pragma unroll
                for (int nt = 0; nt < 4; ++nt)
                    acc[mt][nt] = __builtin_amdgcn_mfma_f32_16x16x32_bf16(
                        av[ks][mt], bv[ks][nt], acc[mt][nt], 0, 0, 0);
    }

    // epilogue: D row = fq*4+reg, col = fm (verified r4-r7)
#pragma unroll
    for (int mt = 0; mt < MT; mt++) {
        int row0 = bm + wr * (BM / 2) + mt * 16 + fq * 4;
#pragma unroll
        for (int nt = 0; nt < 4; nt++) {
            int col = bn + wc * 64 + nt * 16 + fm;
            float bsv = BIAS ? bias[col] : 0.f;
#pragma unroll
            for (int r = 0; r < 4; r++) {
                float val = acc[mt][nt][r] + bsv;
                if (RELU) val = fmaxf(val, 0.f);
                if constexpr (sizeof(TC) == 4)
                    ((float*)C)[(size_t)(row0 + r) * N + col] = val;
                else
                    ((ushort*)C)[(size_t)(row0 + r) * N + col] = f2bf(val);
            }
        }
    }
}

// (256,2): natural allocation (~164 VGPR) reaches 3 waves/SIMD; (256,3)
// forced spills (r7, +9us). Verified best config.
template <int BM, typename TC, bool RELU>
__global__ __launch_bounds__(256, 2) void gemm_bf(const ushort* __restrict__ A,
                                                  const ushort* __restrict__ Bm,
                                                  const float* __restrict__ bias,
                                                  TC* __restrict__ C,
                                                  int N, int K) {
    gemm_core<BM, TC, RELU, true, false>(A, K, Bm, K, bias, C, N, K,
                                         blockIdx.y * BM, blockIdx.x * 128);
}

// ---------- z-batched QKV projection + piggyback weight convert -------------
// z<3: the 3 QKV GEMMs (BM=128, fp32-A converted in-staging). z==3: Wo/W1/W2
// fp32->bf16 convert as a grid-stride slice (those weights are consumed >=2
// dispatches later; stream order guarantees visibility). The 256 convert
// blocks backfill CUs as the 768 GEMM blocks drain -> the former 10-15us
// standalone convert rides for ~free.
struct QkvArgs {
    const float* A[3]; const ushort* B[3]; const float* bias[3]; ushort* C[3];
    const float* cs[3]; ushort* cd[3]; unsigned int cn[3];   // convert: src/dst/chunks
};
__global__ __launch_bounds__(256, 2) void gemm_qkv(QkvArgs qa) {
    const int g = blockIdx.z;
    if (g == 3) {   // convert slice: 256 blocks x 256 thr, 8 elems/chunk
        const unsigned int gtid = (blockIdx.y * 8 + blockIdx.x) * 256 + threadIdx.x;
        const unsigned int total = qa.cn[0] + qa.cn[1] + qa.cn[2];
        for (unsigned int c = gtid; c < total; c += 65536) {
            unsigned int off = c; int seg = 0;
            if (off >= qa.cn[0]) { off -= qa.cn[0]; seg = 1; }
            if (seg == 1 && off >= qa.cn[1]) { off -= qa.cn[1]; seg = 2; }
            const float* s = qa.cs[seg] + (size_t)off * 8;
            float4 f0 = *(const float4*)(s);
            float4 f1 = *(const float4*)(s + 4);
            *(short8*)(qa.cd[seg] + (size_t)off * 8) = pack8(f0, f1);
        }
        return;     // no barriers executed in this branch (block-uniform)
    }
    gemm_core<128, ushort, false, true, true>(qa.A[g], DDIM, qa.B[g], DDIM,
                                              qa.bias[g], qa.C[g], DDIM, DDIM,
                                              blockIdx.y * 128, blockIdx.x * 128);
}

// ---------- split-K GEMMs (N=1024 shapes) ----------
// Wo: split-2 (K=1024 -> 512/slice). W2: split-4 (K=4096 -> 1024/slice):
// 512 blocks = 2/CU was 1/3 under the 3-blocks/CU VGPR cap; 1024 blocks
// -> 3/CU resident + backfill. Partials reduced (+bias) in the next add_ln.
struct SkArgs { const ushort* A; const ushort* Bm; float* C0; float* C1; int lda; int Klen; };
__global__ __launch_bounds__(256, 2) void gemm_splitk(SkArgs s) {
    const int z = blockIdx.z;
    float* C = z ? s.C1 : s.C0;
    gemm_core<128, float, false, false, false>(s.A + z * s.Klen, s.lda,
                                               s.Bm + z * s.Klen, s.lda,
                                               nullptr, C, DDIM, s.Klen,
                                               blockIdx.y * 128, blockIdx.x * 128);
}
struct Sk4Args { const ushort* A; const ushort* Bm; float* C[4]; int lda; int Klen; };
__global__ __launch_bounds__(256, 2) void gemm_splitk4(Sk4Args s) {
    const int z = blockIdx.z;
    gemm_core<128, float, false, false, false>(s.A + z * s.Klen, s.lda,
                                               s.Bm + z * s.Klen, s.lda,
                                               nullptr, s.C[z], DDIM, s.Klen,
                                               blockIdx.y * 128, blockIdx.x * 128);
}

// ---------- flash-style attention with distance decay (bf16 in/out) ----------
// (frozen since r8 — dbuf K staging, decode v3; ~80us, dependency-bound;
// 4 structural attempts bracket this structure at 80-84us)
__global__ __launch_bounds__(256, 4) void attn_flash(
    const ushort* __restrict__ Q, const ushort* __restrict__ Kg,
    const ushort* __restrict__ Vg, const float* __restrict__ gammas,
    const int* __restrict__ maskp, ushort* __restrict__ out) {
    __shared__ short QP[64 * 72];        // 9.2 KB: Q tile; pass2: P tiles
    __shared__ short KsD[2][64 * 64];    // 16 KB: K chunk double buffer
    __shared__ short Vts[64 * 72];       // 9.2 KB: V chunk transposed [d][j]

    const int t = threadIdx.x;
    const int lane = t & 63, w = t >> 6;
    const int col = lane & 15;
    const int quad = lane >> 4;
    const int srl = lane >> 3;                 // staging row-in-group
    const int sg8 = ((lane & 7) ^ srl) << 3;   // swizzled global d offset
    const int swk = col & 7;                   // read-side swizzle

    const int bid = blockIdx.x;
    const int xcls = bid & 7;
    const int m = bid >> 3;
    const int bh = xcls + ((m & 7) << 3);
    const int itr = m >> 3;
    const int yy = itr & 3, jj = itr >> 2;
    const int it = (((yy + jj) & 3) << 2) + ((2 * yy + jj) & 3);
    const int h = bh & (HH - 1);
    const int b = bh >> 4;
    const int i0 = it * 64;
    const int mask = *maskp;

    const float LOG2E = 1.44269504f;
    const float SC2 = 0.125f * LOG2E;    // score scale folded into log2 domain
    const float g0 = gammas[h];
    const float gnat = -((g0 > 20.f) ? g0 : log1pf(__expf(g0)));
    const float g2 = gnat * LOG2E;       // decay exponent in log2 domain

    const size_t qbase = ((size_t)(b * SS + i0)) * DDIM + h * DKK;
    const size_t kvbase = ((size_t)b * SS) * DDIM + h * DKK;

#define STAGE_K(jc, kb) \
    { _Pragma("unroll") for (int p = 0; p < 2; ++p) { \
        int rowg = (w * 2 + p) * 8; \
        GLD16(Kg + kvbase + (size_t)((jc) + rowg + srl) * DDIM + sg8, \
              &KsD[kb][rowg * 64]); } }

    {   // stage Q tile into QP + prefetch K chunk 0
        int r = t >> 2, d0 = (t & 3) << 4;
        const ushort* gq = Q + qbase + (size_t)r * DDIM + d0;
        *(short8*)&QP[r * 72 + d0]     = *(const short8*)(gq);
        *(short8*)&QP[r * 72 + d0 + 8] = *(const short8*)(gq + 8);
        STAGE_K(0, 0);
    }
    __syncthreads();
    const short8 qa0 = *(const short8*)&QP[(w * 16 + col) * 72 + quad * 8];
    const short8 qa1 = *(const short8*)&QP[(w * 16 + col) * 72 + 32 + quad * 8];

    float m1[4], su[4], smT[4], gi4[4];
    int lim4[4];
#pragma unroll
    for (int r = 0; r < 4; ++r) {
        m1[r] = -3.4e38f; su[r] = 0.f; smT[r] = 0.f;
        int gi = i0 + w * 16 + quad * 4 + r;
        gi4[r] = (float)gi;
        lim4[r] = gi + mask;
    }

    int buf = 0;
    // ======== pass 1: row max + unshifted (unmasked, masked) exp2 sums ======
    for (int ck = 0; ck < SS / JC2; ++ck) {
        const int jc = ck * JC2;
        const int njc = ((ck + 1) & 15) * JC2;   // ck=15 -> chunk 0 for pass 2
        STAGE_K(njc, buf ^ 1);
#pragma unroll
        for (int g = 0; g < 4; ++g) {
            const short* Kr = &KsD[buf][(g * 16 + col) * 64];
            short8 kb0 = *(const short8*)&Kr[(quad ^ swk) << 3];
            short8 kb1 = *(const short8*)&Kr[((4 + quad) ^ swk) << 3];
            f32x4 c = (f32x4){0.f, 0.f, 0.f, 0.f};
            c = __builtin_amdgcn_mfma_f32_16x16x32_bf16(qa0, kb0, c, 0, 0, 0);
            c = __builtin_amdgcn_mfma_f32_16x16x32_bf16(qa1, kb1, c, 0, 0, 0);
            int j = jc + g * 16 + col;
#pragma unroll
            for (int r = 0; r < 4; ++r) {
                float s2 = c[r] * SC2;               // score in log2 units
                m1[r] = fmaxf(m1[r], s2);
                float ev = fexp2(s2);                // = exp(score)
                su[r] += ev;
                smT[r] += (j < lim4[r]) ? ev : 0.f;
            }
        }
        __syncthreads();
        buf ^= 1;
    }
    // merge across the 16-lane col group (once)
#pragma unroll
    for (int off = 1; off < 16; off <<= 1) {
#pragma unroll
        for (int r = 0; r < 4; ++r) {
            m1[r] = fmaxf(m1[r], __shfl_xor(m1[r], off, 16));
            su[r] += __shfl_xor(su[r], off, 16);
            smT[r] += __shfl_xor(smT[r], off, 16);
        }
    }
    float lse2[4], smTn[4], ms2[4];
#pragma unroll
    for (int r = 0; r < 4; ++r) {
        lse2[r] = __log2f(su[r]);                    // log2(sum exp)
        smTn[r] = smT[r] / su[r];                    // = disttot (normalized)
        ms2[r]  = fmaxf(m1[r], 0.f);                 // static shift for softmax#2
    }

    // ======== pass 2: recompute + cumsum + decay + static-shift softmax + PV =
    const int nck2 = min(SS / JC2, max(1, (i0 + 62 + mask) / 64 + 1));

    float l2[4], carry[4];
    f32x4 o[4];
#pragma unroll
    for (int r = 0; r < 4; ++r) { l2[r] = 0.f; carry[r] = 0.f; }
#pragma unroll
    for (int dg = 0; dg < 4; ++dg) o[dg] = (f32x4){0.f, 0.f, 0.f, 0.f};

    short* Pw = &QP[w * 16 * 72];

    for (int ck = 0; ck < nck2; ++ck) {
        const int jc = ck * JC2;
        if (ck + 1 < nck2) STAGE_K((ck + 1) * JC2, buf ^ 1);
        {   // stage V chunk transposed: Vts[d][j]
            int j = t & 63, dq = t >> 6, d0 = dq * 16;
            const ushort* gv = Vg + kvbase + (size_t)(jc + j) * DDIM + d0;
            short8 v0 = *(const short8*)(gv);
            short8 v1 = *(const short8*)(gv + 8);
#pragma unroll
            for (int k = 0; k < 8; ++k) {
                Vts[(d0 + k) * 72 + j]     = v0[k];
                Vts[(d0 + 8 + k) * 72 + j] = v1[k];
            }
        }

#pragma unroll
        for (int g = 0; g < 4; ++g) {
            const short* Kr = &KsD[buf][(g * 16 + col) * 64];
            short8 kb0 = *(const short8*)&Kr[(quad ^ swk) << 3];
            short8 kb1 = *(const short8*)&Kr[((4 + quad) ^ swk) << 3];
            f32x4 c = (f32x4){0.f, 0.f, 0.f, 0.f};
            c = __builtin_amdgcn_mfma_f32_16x16x32_bf16(qa0, kb0, c, 0, 0, 0);
            c = __builtin_amdgcn_mfma_f32_16x16x32_bf16(qa1, kb1, c, 0, 0, 0);
            const int j = jc + g * 16 + col;
            const float jf = (float)j;
#pragma unroll
            for (int r = 0; r < 4; ++r) {
                float s2 = c[r] * SC2;
                float pj = fexp2(s2 - lse2[r]);      // exact softmax prob
                float incl = (j < lim4[r]) ? pj : 0.f;
                incl = scan16(incl);                 // inclusive prefix (DPP)
                float tot = bcast15(incl);           // group total (lane 15)
                float Cc = carry[r] + incl;          // = distcum
                carry[r] += tot;
                float pos = fabsf(jf - gi4[r]);
                float d2 = fmaxf((smTn[r] - Cc) * pos, 0.f);
                float dist = __builtin_amdgcn_sqrtf(d2);
                float eff = fmaxf(fexp2(g2 * dist), 1e-5f);   // <=1 always
                float pe = fexp2(s2 * eff - ms2[r]);          // <=1 always
                float p = (j < lim4[r]) ? pe : 0.f;
                l2[r] += p;
                Pw[(quad * 4 + r) * 72 + g * 16 + col] = (short)f2bf(p);
            }
        }
        __syncthreads();   // P + V writes visible; drains K prefetch
#pragma unroll
        for (int kg = 0; kg < 2; ++kg) {
            short8 pa = *(const short8*)&Pw[col * 72 + kg * 32 + quad * 8];
#pragma unroll
            for (int dg = 0; dg < 4; ++dg) {
                short8 vb = *(const short8*)&Vts[(dg * 16 + col) * 72 + kg * 32 + quad * 8];
                o[dg] = __builtin_amdgcn_mfma_f32_16x16x32_bf16(pa, vb, o[dg], 0, 0, 0);
            }
        }
        __syncthreads();   // Vts/Pw/Kbuf reuse safety for next iter
        buf ^= 1;
    }

    // final l2 reduce across the 16-lane col group (once)
#pragma unroll
    for (int off = 1; off < 16; off <<= 1)
#pragma unroll
        for (int r = 0; r < 4; ++r) l2[r] += __shfl_xor(l2[r], off, 16);

#pragma unroll
    for (int r = 0; r < 4; ++r) {
        int irow = i0 + w * 16 + quad * 4 + r;
        float scl = 1.f / l2[r];
        if (mask == 0 && irow == 0) scl = 0.f;
        size_t base = ((size_t)(b * SS) + irow) * DDIM + h * DKK;
#pragma unroll
        for (int dg = 0; dg < 4; ++dg)
            out[base + dg * 16 + col] = f2bf(o[dg][r] * scl);
    }
#undef STAGE_K
}

// ---------- fused residual-add + NY-partial reduce + bias + LayerNorm -------
// float4-vectorized; x in registers (one float4/thread @ DDIM=1024/256thr).
template <bool WB, int NY>
__global__ __launch_bounds__(256) void add_ln(const float* __restrict__ R,
                                              const float* __restrict__ Y0,
                                              const float* __restrict__ Y1,
                                              const float* __restrict__ Y2,
                                              const float* __restrict__ Y3,
                                              const float* __restrict__ gb,
                                              const float* __restrict__ w,
                                              const float* __restrict__ bb,
                                              float* __restrict__ out,
                                              ushort* __restrict__ obf) {
    const int row = blockIdx.x;
    const int tid = threadIdx.x;
    __shared__ float red[4];
    const size_t base = (size_t)row * DDIM;
    const int i4 = tid * 4;
    float4 a  = *(const float4*)(R  + base + i4);
    float4 y0 = *(const float4*)(Y0 + base + i4);
    float4 y1 = *(const float4*)(Y1 + base + i4);
    float4 g  = *(const float4*)(gb + i4);
    float4 x;
    x.x = a.x + y0.x + y1.x + g.x;
    x.y = a.y + y0.y + y1.y + g.y;
    x.z = a.z + y0.z + y1.z + g.z;
    x.w = a.w + y0.w + y1.w + g.w;
    if constexpr (NY == 4) {
        float4 y2 = *(const float4*)(Y2 + base + i4);
        float4 y3 = *(const float4*)(Y3 + base + i4);
        x.x += y2.x + y3.x; x.y += y2.y + y3.y;
        x.z += y2.z + y3.z; x.w += y2.w + y3.w;
    }
    float s  = (x.x + x.y) + (x.z + x.w);
    float s2 = (x.x * x.x + x.y * x.y) + (x.z * x.z + x.w * x.w);
    s = block_reduce_sum(s, red, tid);
    s2 = block_reduce_sum(s2, red, tid);
    const float mu = s * (1.f / DDIM);
    const float var = s2 * (1.f / DDIM) - mu * mu;
    const float rstd = rsqrtf(var + 1e-5f);
    float4 wv = *(const float4*)(w + i4);
    float4 bv = *(const float4*)(bb + i4);
    float4 v;
    v.x = (x.x - mu) * rstd * wv.x + bv.x;
    v.y = (x.y - mu) * rstd * wv.y + bv.y;
    v.z = (x.z - mu) * rstd * wv.z + bv.z;
    v.w = (x.w - mu) * rstd * wv.w + bv.w;
    *(float4*)(out + base + i4) = v;
    if (WB) {
        ushort4 o4;
        o4.x = f2bf(v.x); o4.y = f2bf(v.y); o4.z = f2bf(v.z); o4.w = f2bf(v.w);
        *(ushort4*)(obf + base + i4) = o4;
    }
}

extern "C" void kernel_launch(void* const* d_in, const int* in_sizes, int n_in,
                              void* d_out, int out_size, void* d_ws, size_t ws_size,
                              hipStream_t stream) {
    const int*   maskp  = (const int*)d_in[0];
    const float* query  = (const float*)d_in[1];
    const float* key    = (const float*)d_in[2];
    const float* values = (const float*)d_in[3];
    const float* Wq = (const float*)d_in[4];
    const float* bq = (const float*)d_in[5];
    const float* Wk = (const float*)d_in[6];
    const float* bk = (const float*)d_in[7];
    const float* Wv = (const float*)d_in[8];
    const float* bv = (const float*)d_in[9];
    const float* Wo = (const float*)d_in[10];
    const float* bo = (const float*)d_in[11];
    const float* gammas = (const float*)d_in[12];
    const float* ln1w = (const float*)d_in[13];
    const float* ln1b = (const float*)d_in[14];
    const float* W1 = (const float*)d_in[15];
    const float* b1 = (const float*)d_in[16];
    const float* W2 = (const float*)d_in[17];
    const float* b2 = (const float*)d_in[18];
    const float* ln2w = (const float*)d_in[19];
    const float* ln2b = (const float*)d_in[20];

    const int M = BB * SS;                 // 4096 rows
    const size_t MB = 1048576;
    char* wsb = (char*)d_ws;
    ushort* Wq_bf = (ushort*)(wsb + 0 * MB);
    ushort* Wk_bf = (ushort*)(wsb + 8 * MB);
    ushort* Wv_bf = (ushort*)(wsb + 16 * MB);
    ushort* Wo_bf = (ushort*)(wsb + 24 * MB);
    ushort* W1_bf = (ushort*)(wsb + 32 * MB);
    ushort* W2_bf = (ushort*)(wsb + 40 * MB);
    ushort* Qb    = (ushort*)(wsb + 72 * MB);
    ushort* Kb    = (ushort*)(wsb + 80 * MB);
    ushort* Vb    = (ushort*)(wsb + 88 * MB);
    ushort* ATTb  = (ushort*)(wsb + 96 * MB);
    float*  Ysp0  = (float*)(wsb + 104 * MB);   // split partial 0 (16 MiB)
    float*  Ysp1  = (float*)(wsb + 120 * MB);   // split partial 1 (16 MiB)
    float*  Ysp2  = (float*)(wsb + 0 * MB);     // W2 partial 2: aliases Wq/Wk_bf
                                                // slots (dead after QKV)
    float*  Ysp3  = (float*)(wsb + 16 * MB);    // W2 partial 3: aliases Wv/Wo_bf
                                                // slots (dead after QKV/Wo)
    float*  xf    = (float*)(wsb + 48 * MB);    // fp32 x (16 MiB)
    ushort* x_bf  = (ushort*)(wsb + 64 * MB);   // bf16 x (8 MiB)
    ushort* hidden= (ushort*)(wsb + 72 * MB);   // alias Q/K/V/ATT (dead)

    dim3 blk(256);

    // slim convert: Wq/Wk/Wv only (needed by the very next dispatch)
    CvtArgs ca;
    ca.s[0] = Wq; ca.s[1] = Wk; ca.s[2] = Wv;
    ca.d[0] = Wq_bf; ca.d[1] = Wk_bf; ca.d[2] = Wv_bf;
    convert_bf<<<dim3(512, 3), blk, 0, stream>>>(ca);

    // QKV projections (z<3) + Wo/W1/W2 convert piggyback (z==3)
    QkvArgs qa;
    qa.A[0] = query; qa.A[1] = key; qa.A[2] = values;
    qa.B[0] = Wq_bf; qa.B[1] = Wk_bf; qa.B[2] = Wv_bf;
    qa.bias[0] = bq; qa.bias[1] = bk; qa.bias[2] = bv;
    qa.C[0] = Qb; qa.C[1] = Kb; qa.C[2] = Vb;
    qa.cs[0] = Wo; qa.cs[1] = W1; qa.cs[2] = W2;
    qa.cd[0] = Wo_bf; qa.cd[1] = W1_bf; qa.cd[2] = W2_bf;
    qa.cn[0] = (1024u * 1024) / 8;             // Wo chunks
    qa.cn[1] = (4096u * 1024) / 8;             // W1 chunks
    qa.cn[2] = (4096u * 1024) / 8;             // W2 chunks
    gemm_qkv<<<dim3(8, 32, 4), blk, 0, stream>>>(qa);

    // attention (flash-style, bf16 in/out)
    attn_flash<<<dim3(BB * HH * 16), blk, 0, stream>>>(Qb, Kb, Vb, gammas, maskp, ATTb);

    // output projection, split-K=2 (N=1024, K=1024): partials -> Ysp0/Ysp1
    {
        SkArgs s; s.A = ATTb; s.Bm = Wo_bf; s.C0 = Ysp0; s.C1 = Ysp1;
        s.lda = DDIM; s.Klen = DDIM / 2;
        gemm_splitk<<<dim3(8, 32, 2), blk, 0, stream>>>(s);
    }

    // x = LN(query + Ysp0 + Ysp1 + bo) -> xf fp32 + x_bf
    add_ln<true, 2><<<dim3(M), blk, 0, stream>>>(query, Ysp0, Ysp1, nullptr, nullptr,
                                                 bo, ln1w, ln1b, xf, x_bf);

    // hidden = relu(x @ W1^T + b1) -> bf16 (verified r8 config)
    gemm_bf<128, ushort, true><<<dim3(32, 32), blk, 0, stream>>>(x_bf, W1_bf, b1, hidden, DFFF, DDIM);

    // y = hidden @ W2^T, split-K=4 (N=1024, K=4096): 1024 blocks -> 3/CU cap
    {
        Sk4Args s; s.A = hidden; s.Bm = W2_bf;
        s.C[0] = Ysp0; s.C[1] = Ysp1; s.C[2] = Ysp2; s.C[3] = Ysp3;
        s.lda = DFFF; s.Klen = DFFF / 4;
        gemm_splitk4<<<dim3(8, 32, 4), blk, 0, stream>>>(s);
    }

    // out = LN(x + Ysp0..3 + b2) -> d_out (fp32)
    add_ln<false, 4><<<dim3(M), blk, 0, stream>>>(xf, Ysp0, Ysp1, Ysp2, Ysp3,
                                                  b2, ln2w, ln2b, (float*)d_out, nullptr);
}

// Round 12
// 386.286 us; speedup vs baseline: 1.1233x; 1.1233x over previous
//
#include <hip/hip_runtime.h>
#include <hip/hip_bf16.h>
#include <math.h>

#define BB   4
#define SS   1024
#define DDIM 1024
#define HH   16
#define DKK  64
#define DFFF 4096
#define JC2  64      // K/V j-chunk per LDS stage (attention)

typedef __attribute__((ext_vector_type(8))) short short8;
typedef __attribute__((ext_vector_type(4))) float f32x4;
typedef unsigned short ushort;

__device__ __forceinline__ ushort f2bf(float f) {   // RNE fp32->bf16
    unsigned int u = __float_as_uint(f);
    unsigned int r = (u + 0x7FFFu + ((u >> 16) & 1u)) >> 16;
    return (ushort)r;
}
__device__ __forceinline__ short8 pack8(float4 f0, float4 f1) {
    short8 s;
    s[0] = (short)f2bf(f0.x); s[1] = (short)f2bf(f0.y);
    s[2] = (short)f2bf(f0.z); s[3] = (short)f2bf(f0.w);
    s[4] = (short)f2bf(f1.x); s[5] = (short)f2bf(f1.y);
    s[6] = (short)f2bf(f1.z); s[7] = (short)f2bf(f1.w);
    return s;
}

// async global->LDS, 16B per lane; LDS dest = wave-uniform base + lane*16
#define GLD16(g, l) __builtin_amdgcn_global_load_lds( \
    (const __attribute__((address_space(1))) unsigned int*)(g), \
    (__attribute__((address_space(3))) unsigned int*)(l), 16, 0, 0)

// exp2 via raw v_exp_f32 (base-2 hardware transcendental)
__device__ __forceinline__ float fexp2(float x) { return __builtin_amdgcn_exp2f(x); }

// inclusive 16-lane prefix sum via DPP row_shr (4 VALU ops, no LDS pipe).
__device__ __forceinline__ float scan16(float x) {
    x += __int_as_float(__builtin_amdgcn_update_dpp(0, __float_as_int(x), 0x111, 0xF, 0xF, true));
    x += __int_as_float(__builtin_amdgcn_update_dpp(0, __float_as_int(x), 0x112, 0xF, 0xF, true));
    x += __int_as_float(__builtin_amdgcn_update_dpp(0, __float_as_int(x), 0x114, 0xF, 0xF, true));
    x += __int_as_float(__builtin_amdgcn_update_dpp(0, __float_as_int(x), 0x118, 0xF, 0xF, true));
    return x;
}
// broadcast lane 15 of each 16-group: ds_swizzle bit-mode, and=0x10 or=0x0F xor=0
__device__ __forceinline__ float bcast15(float x) {
    return __int_as_float(__builtin_amdgcn_ds_swizzle(__float_as_int(x), 0x1F0));
}

// ---------- block reductions (256 threads = 4 waves of 64) ----------
__device__ __forceinline__ float block_reduce_sum(float v, float* red, int tid) {
#pragma unroll
    for (int off = 32; off; off >>= 1) v += __shfl_xor(v, off);
    __syncthreads();
    if ((tid & 63) == 0) red[tid >> 6] = v;
    __syncthreads();
    return red[0] + red[1] + red[2] + red[3];
}

// ---------- fp32 -> bf16 batch convert (q/k/v inputs + all 6 weights) -------
// r12: back to standalone full convert (r11's piggyback serialized ~30us at
// the QKV dispatch tail). bf16 A also halves QKV's A-stream (L2-resident
// across the 8 column-block passes; r11 counters showed 218MB FETCH from
// fp32-A re-fetch) and re-enables the faster GLD16 staging (m151).
struct CvtArgs { const float* s[9]; ushort* d[9]; unsigned int n[9]; };
__global__ __launch_bounds__(256) void convert_bf(CvtArgs a) {
    const int seg = blockIdx.y;
    size_t idx = ((size_t)blockIdx.x * 256 + threadIdx.x) * 8;
    if (idx >= a.n[seg]) return;
    const float* s = a.s[seg];
    float4 f0 = *(const float4*)(s + idx);
    float4 f1 = *(const float4*)(s + idx + 4);
    *(short8*)(a.d[seg] + idx) = pack8(f0, f1);
}

// ---------- bf16 MFMA GEMM core (m97-style): C = act(A @ W^T [+ b]) ---------
template <int BM, typename TC, bool RELU, bool BIAS>
__device__ __forceinline__ void gemm_core(const ushort* __restrict__ A, int lda,
                                          const ushort* __restrict__ Bm, int ldb,
                                          const float* __restrict__ bias,
                                          TC* __restrict__ C, int N, int Klen,
                                          int bm, int bn) {
    constexpr int MT = BM / 32;           // m-frags per wave
    constexpr int PA = BM / 32;           // A staging iters per wave
    __shared__ ushort A_s[BM * 64];
    __shared__ ushort B_s[128 * 64];
    const int t = threadIdx.x;
    const int lane = t & 63, w = t >> 6;
    const int wr = w >> 1, wc = w & 1;
    const int fm = lane & 15, fq = lane >> 4;
    const int srl = lane >> 3;            // staging row-in-group
    const int sg8 = ((lane & 7) ^ srl) << 3;   // swizzled global k offset

    f32x4 acc[MT][4];
#pragma unroll
    for (int mt = 0; mt < MT; mt++)
#pragma unroll
        for (int nt = 0; nt < 4; nt++) acc[mt][nt] = (f32x4){0.f, 0.f, 0.f, 0.f};

    for (int kt = 0; kt < Klen; kt += 64) {
        __syncthreads();
#pragma unroll
        for (int p = 0; p < PA; ++p) {
            int rowg = (w * PA + p) * 8;
            GLD16(A + (size_t)(bm + rowg + srl) * lda + kt + sg8, &A_s[rowg * 64]);
        }
#pragma unroll
        for (int p = 0; p < 4; ++p) {
            int rowg = (w * 4 + p) * 8;
            GLD16(Bm + (size_t)(bn + rowg + srl) * ldb + kt + sg8, &B_s[rowg * 64]);
        }
        __syncthreads();                  // drains vmcnt (incl. lds-DMA)

        short8 av[2][MT], bv[2][4];
        const int sw = fm & 7;
#pragma unroll
        for (int mt = 0; mt < MT; ++mt) {
            int row = wr * (BM / 2) + mt * 16 + fm;
#pragma unroll
            for (int ks = 0; ks < 2; ++ks)
                av[ks][mt] = *(const short8*)&A_s[row * 64 + (((ks * 4 + fq) ^ sw) << 3)];
        }
#pragma unroll
        for (int nt = 0; nt < 4; ++nt) {
            int row = wc * 64 + nt * 16 + fm;
#pragma unroll
            for (int ks = 0; ks < 2; ++ks)
                bv[ks][nt] = *(const short8*)&B_s[row * 64 + (((ks * 4 + fq) ^ sw) << 3)];
        }
#pragma unroll
        for (int ks = 0; ks < 2; ++ks)
#pragma unroll
            for (int mt = 0; mt < MT; ++mt)
#pragma unroll
                for (int nt = 0; nt < 4; ++nt)
                    acc[mt][nt] = __builtin_amdgcn_mfma_f32_16x16x32_bf16(
                        av[ks][mt], bv[ks][nt], acc[mt][nt], 0, 0, 0);
    }

    // epilogue: D row = fq*4+reg, col = fm (verified r4-r7)
#pragma unroll
    for (int mt = 0; mt < MT; mt++) {
        int row0 = bm + wr * (BM / 2) + mt * 16 + fq * 4;
#pragma unroll
        for (int nt = 0; nt < 4; nt++) {
            int col = bn + wc * 64 + nt * 16 + fm;
            float bsv = BIAS ? bias[col] : 0.f;
#pragma unroll
            for (int r = 0; r < 4; r++) {
                float val = acc[mt][nt][r] + bsv;
                if (RELU) val = fmaxf(val, 0.f);
                if constexpr (sizeof(TC) == 4)
                    ((float*)C)[(size_t)(row0 + r) * N + col] = val;
                else
                    ((ushort*)C)[(size_t)(row0 + r) * N + col] = f2bf(val);
            }
        }
    }
}

// (256,2): natural allocation (~164 VGPR) reaches 3 waves/SIMD; (256,3)
// forced spills (r7, +9us). Verified best config.
template <int BM, typename TC, bool RELU>
__global__ __launch_bounds__(256, 2) void gemm_bf(const ushort* __restrict__ A,
                                                  const ushort* __restrict__ Bm,
                                                  const float* __restrict__ bias,
                                                  TC* __restrict__ C,
                                                  int N, int K) {
    gemm_core<BM, TC, RELU, true>(A, K, Bm, K, bias, C, N, K,
                                  blockIdx.y * BM, blockIdx.x * 128);
}

// ---------- z-batched QKV projection (bf16 A, GLD16 staging) ----------------
struct QkvArgs { const ushort* A[3]; const ushort* B[3]; const float* bias[3]; ushort* C[3]; };
__global__ __launch_bounds__(256, 2) void gemm_qkv(QkvArgs qa) {
    const int g = blockIdx.z;
    gemm_core<128, ushort, false, true>(qa.A[g], DDIM, qa.B[g], DDIM,
                                        qa.bias[g], qa.C[g], DDIM, DDIM,
                                        blockIdx.y * 128, blockIdx.x * 128);
}

// ---------- split-K GEMM (N=1024 shapes: Wo, W2; split-2, verified) ---------
struct SkArgs { const ushort* A; const ushort* Bm; float* C0; float* C1; int lda; int Klen; };
__global__ __launch_bounds__(256, 2) void gemm_splitk(SkArgs s) {
    const int z = blockIdx.z;
    float* C = z ? s.C1 : s.C0;
    gemm_core<128, float, false, false>(s.A + z * s.Klen, s.lda,
                                        s.Bm + z * s.Klen, s.lda,
                                        nullptr, C, DDIM, s.Klen,
                                        blockIdx.y * 128, blockIdx.x * 128);
}

// ---------- flash-style attention with distance decay (bf16 in/out) ----------
// (frozen since r8 — dbuf K staging, decode v3; ~80us, dependency-bound)
__global__ __launch_bounds__(256, 4) void attn_flash(
    const ushort* __restrict__ Q, const ushort* __restrict__ Kg,
    const ushort* __restrict__ Vg, const float* __restrict__ gammas,
    const int* __restrict__ maskp, ushort* __restrict__ out) {
    __shared__ short QP[64 * 72];        // 9.2 KB: Q tile; pass2: P tiles
    __shared__ short KsD[2][64 * 64];    // 16 KB: K chunk double buffer
    __shared__ short Vts[64 * 72];       // 9.2 KB: V chunk transposed [d][j]

    const int t = threadIdx.x;
    const int lane = t & 63, w = t >> 6;
    const int col = lane & 15;
    const int quad = lane >> 4;
    const int srl = lane >> 3;                 // staging row-in-group
    const int sg8 = ((lane & 7) ^ srl) << 3;   // swizzled global d offset
    const int swk = col & 7;                   // read-side swizzle

    const int bid = blockIdx.x;
    const int xcls = bid & 7;
    const int m = bid >> 3;
    const int bh = xcls + ((m & 7) << 3);
    const int itr = m >> 3;
    const int yy = itr & 3, jj = itr >> 2;
    const int it = (((yy + jj) & 3) << 2) + ((2 * yy + jj) & 3);
    const int h = bh & (HH - 1);
    const int b = bh >> 4;
    const int i0 = it * 64;
    const int mask = *maskp;

    const float LOG2E = 1.44269504f;
    const float SC2 = 0.125f * LOG2E;    // score scale folded into log2 domain
    const float g0 = gammas[h];
    const float gnat = -((g0 > 20.f) ? g0 : log1pf(__expf(g0)));
    const float g2 = gnat * LOG2E;       // decay exponent in log2 domain

    const size_t qbase = ((size_t)(b * SS + i0)) * DDIM + h * DKK;
    const size_t kvbase = ((size_t)b * SS) * DDIM + h * DKK;

#define STAGE_K(jc, kb) \
    { _Pragma("unroll") for (int p = 0; p < 2; ++p) { \
        int rowg = (w * 2 + p) * 8; \
        GLD16(Kg + kvbase + (size_t)((jc) + rowg + srl) * DDIM + sg8, \
              &KsD[kb][rowg * 64]); } }

    {   // stage Q tile into QP + prefetch K chunk 0
        int r = t >> 2, d0 = (t & 3) << 4;
        const ushort* gq = Q + qbase + (size_t)r * DDIM + d0;
        *(short8*)&QP[r * 72 + d0]     = *(const short8*)(gq);
        *(short8*)&QP[r * 72 + d0 + 8] = *(const short8*)(gq + 8);
        STAGE_K(0, 0);
    }
    __syncthreads();
    const short8 qa0 = *(const short8*)&QP[(w * 16 + col) * 72 + quad * 8];
    const short8 qa1 = *(const short8*)&QP[(w * 16 + col) * 72 + 32 + quad * 8];

    float m1[4], su[4], smT[4], gi4[4];
    int lim4[4];
#pragma unroll
    for (int r = 0; r < 4; ++r) {
        m1[r] = -3.4e38f; su[r] = 0.f; smT[r] = 0.f;
        int gi = i0 + w * 16 + quad * 4 + r;
        gi4[r] = (float)gi;
        lim4[r] = gi + mask;
    }

    int buf = 0;
    // ======== pass 1: row max + unshifted (unmasked, masked) exp2 sums ======
    for (int ck = 0; ck < SS / JC2; ++ck) {
        const int jc = ck * JC2;
        const int njc = ((ck + 1) & 15) * JC2;   // ck=15 -> chunk 0 for pass 2
        STAGE_K(njc, buf ^ 1);
#pragma unroll
        for (int g = 0; g < 4; ++g) {
            const short* Kr = &KsD[buf][(g * 16 + col) * 64];
            short8 kb0 = *(const short8*)&Kr[(quad ^ swk) << 3];
            short8 kb1 = *(const short8*)&Kr[((4 + quad) ^ swk) << 3];
            f32x4 c = (f32x4){0.f, 0.f, 0.f, 0.f};
            c = __builtin_amdgcn_mfma_f32_16x16x32_bf16(qa0, kb0, c, 0, 0, 0);
            c = __builtin_amdgcn_mfma_f32_16x16x32_bf16(qa1, kb1, c, 0, 0, 0);
            int j = jc + g * 16 + col;
#pragma unroll
            for (int r = 0; r < 4; ++r) {
                float s2 = c[r] * SC2;               // score in log2 units
                m1[r] = fmaxf(m1[r], s2);
                float ev = fexp2(s2);                // = exp(score)
                su[r] += ev;
                smT[r] += (j < lim4[r]) ? ev : 0.f;
            }
        }
        __syncthreads();
        buf ^= 1;
    }
    // merge across the 16-lane col group (once)
#pragma unroll
    for (int off = 1; off < 16; off <<= 1) {
#pragma unroll
        for (int r = 0; r < 4; ++r) {
            m1[r] = fmaxf(m1[r], __shfl_xor(m1[r], off, 16));
            su[r] += __shfl_xor(su[r], off, 16);
            smT[r] += __shfl_xor(smT[r], off, 16);
        }
    }
    float lse2[4], smTn[4], ms2[4];
#pragma unroll
    for (int r = 0; r < 4; ++r) {
        lse2[r] = __log2f(su[r]);                    // log2(sum exp)
        smTn[r] = smT[r] / su[r];                    // = disttot (normalized)
        ms2[r]  = fmaxf(m1[r], 0.f);                 // static shift for softmax#2
    }

    // ======== pass 2: recompute + cumsum + decay + static-shift softmax + PV =
    const int nck2 = min(SS / JC2, max(1, (i0 + 62 + mask) / 64 + 1));

    float l2[4], carry[4];
    f32x4 o[4];
#pragma unroll
    for (int r = 0; r < 4; ++r) { l2[r] = 0.f; carry[r] = 0.f; }
#pragma unroll
    for (int dg = 0; dg < 4; ++dg) o[dg] = (f32x4){0.f, 0.f, 0.f, 0.f};

    short* Pw = &QP[w * 16 * 72];

    for (int ck = 0; ck < nck2; ++ck) {
        const int jc = ck * JC2;
        if (ck + 1 < nck2) STAGE_K((ck + 1) * JC2, buf ^ 1);
        {   // stage V chunk transposed: Vts[d][j]
            int j = t & 63, dq = t >> 6, d0 = dq * 16;
            const ushort* gv = Vg + kvbase + (size_t)(jc + j) * DDIM + d0;
            short8 v0 = *(const short8*)(gv);
            short8 v1 = *(const short8*)(gv + 8);
#pragma unroll
            for (int k = 0; k < 8; ++k) {
                Vts[(d0 + k) * 72 + j]     = v0[k];
                Vts[(d0 + 8 + k) * 72 + j] = v1[k];
            }
        }

#pragma unroll
        for (int g = 0; g < 4; ++g) {
            const short* Kr = &KsD[buf][(g * 16 + col) * 64];
            short8 kb0 = *(const short8*)&Kr[(quad ^ swk) << 3];
            short8 kb1 = *(const short8*)&Kr[((4 + quad) ^ swk) << 3];
            f32x4 c = (f32x4){0.f, 0.f, 0.f, 0.f};
            c = __builtin_amdgcn_mfma_f32_16x16x32_bf16(qa0, kb0, c, 0, 0, 0);
            c = __builtin_amdgcn_mfma_f32_16x16x32_bf16(qa1, kb1, c, 0, 0, 0);
            const int j = jc + g * 16 + col;
            const float jf = (float)j;
#pragma unroll
            for (int r = 0; r < 4; ++r) {
                float s2 = c[r] * SC2;
                float pj = fexp2(s2 - lse2[r]);      // exact softmax prob
                float incl = (j < lim4[r]) ? pj : 0.f;
                incl = scan16(incl);                 // inclusive prefix (DPP)
                float tot = bcast15(incl);           // group total (lane 15)
                float Cc = carry[r] + incl;          // = distcum
                carry[r] += tot;
                float pos = fabsf(jf - gi4[r]);
                float d2 = fmaxf((smTn[r] - Cc) * pos, 0.f);
                float dist = __builtin_amdgcn_sqrtf(d2);
                float eff = fmaxf(fexp2(g2 * dist), 1e-5f);   // <=1 always
                float pe = fexp2(s2 * eff - ms2[r]);          // <=1 always
                float p = (j < lim4[r]) ? pe : 0.f;
                l2[r] += p;
                Pw[(quad * 4 + r) * 72 + g * 16 + col] = (short)f2bf(p);
            }
        }
        __syncthreads();   // P + V writes visible; drains K prefetch
#pragma unroll
        for (int kg = 0; kg < 2; ++kg) {
            short8 pa = *(const short8*)&Pw[col * 72 + kg * 32 + quad * 8];
#pragma unroll
            for (int dg = 0; dg < 4; ++dg) {
                short8 vb = *(const short8*)&Vts[(dg * 16 + col) * 72 + kg * 32 + quad * 8];
                o[dg] = __builtin_amdgcn_mfma_f32_16x16x32_bf16(pa, vb, o[dg], 0, 0, 0);
            }
        }
        __syncthreads();   // Vts/Pw/Kbuf reuse safety for next iter
        buf ^= 1;
    }

    // final l2 reduce across the 16-lane col group (once)
#pragma unroll
    for (int off = 1; off < 16; off <<= 1)
#pragma unroll
        for (int r = 0; r < 4; ++r) l2[r] += __shfl_xor(l2[r], off, 16);

#pragma unroll
    for (int r = 0; r < 4; ++r) {
        int irow = i0 + w * 16 + quad * 4 + r;
        float scl = 1.f / l2[r];
        if (mask == 0 && irow == 0) scl = 0.f;
        size_t base = ((size_t)(b * SS) + irow) * DDIM + h * DKK;
#pragma unroll
        for (int dg = 0; dg < 4; ++dg)
            out[base + dg * 16 + col] = f2bf(o[dg][r] * scl);
    }
#undef STAGE_K
}

// ---------- fused residual-add + dual-partial reduce + bias + LayerNorm ------
// float4-vectorized; x in registers (one float4/thread @ DDIM=1024/256thr).
template <bool WB>
__global__ __launch_bounds__(256) void add_ln(const float* __restrict__ R,
                                              const float* __restrict__ Y0,
                                              const float* __restrict__ Y1,
                                              const float* __restrict__ gb,
                                              const float* __restrict__ w,
                                              const float* __restrict__ bb,
                                              float* __restrict__ out,
                                              ushort* __restrict__ obf) {
    const int row = blockIdx.x;
    const int tid = threadIdx.x;
    __shared__ float red[4];
    const size_t base = (size_t)row * DDIM;
    const int i4 = tid * 4;
    float4 a  = *(const float4*)(R  + base + i4);
    float4 y0 = *(const float4*)(Y0 + base + i4);
    float4 y1 = *(const float4*)(Y1 + base + i4);
    float4 g  = *(const float4*)(gb + i4);
    float4 x;
    x.x = a.x + y0.x + y1.x + g.x;
    x.y = a.y + y0.y + y1.y + g.y;
    x.z = a.z + y0.z + y1.z + g.z;
    x.w = a.w + y0.w + y1.w + g.w;
    float s  = (x.x + x.y) + (x.z + x.w);
    float s2 = (x.x * x.x + x.y * x.y) + (x.z * x.z + x.w * x.w);
    s = block_reduce_sum(s, red, tid);
    s2 = block_reduce_sum(s2, red, tid);
    const float mu = s * (1.f / DDIM);
    const float var = s2 * (1.f / DDIM) - mu * mu;
    const float rstd = rsqrtf(var + 1e-5f);
    float4 wv = *(const float4*)(w + i4);
    float4 bv = *(const float4*)(bb + i4);
    float4 v;
    v.x = (x.x - mu) * rstd * wv.x + bv.x;
    v.y = (x.y - mu) * rstd * wv.y + bv.y;
    v.z = (x.z - mu) * rstd * wv.z + bv.z;
    v.w = (x.w - mu) * rstd * wv.w + bv.w;
    *(float4*)(out + base + i4) = v;
    if (WB) {
        ushort4 o4;
        o4.x = f2bf(v.x); o4.y = f2bf(v.y); o4.z = f2bf(v.z); o4.w = f2bf(v.w);
        *(ushort4*)(obf + base + i4) = o4;
    }
}

extern "C" void kernel_launch(void* const* d_in, const int* in_sizes, int n_in,
                              void* d_out, int out_size, void* d_ws, size_t ws_size,
                              hipStream_t stream) {
    const int*   maskp  = (const int*)d_in[0];
    const float* query  = (const float*)d_in[1];
    const float* key    = (const float*)d_in[2];
    const float* values = (const float*)d_in[3];
    const float* Wq = (const float*)d_in[4];
    const float* bq = (const float*)d_in[5];
    const float* Wk = (const float*)d_in[6];
    const float* bk = (const float*)d_in[7];
    const float* Wv = (const float*)d_in[8];
    const float* bv = (const float*)d_in[9];
    const float* Wo = (const float*)d_in[10];
    const float* bo = (const float*)d_in[11];
    const float* gammas = (const float*)d_in[12];
    const float* ln1w = (const float*)d_in[13];
    const float* ln1b = (const float*)d_in[14];
    const float* W1 = (const float*)d_in[15];
    const float* b1 = (const float*)d_in[16];
    const float* W2 = (const float*)d_in[17];
    const float* b2 = (const float*)d_in[18];
    const float* ln2w = (const float*)d_in[19];
    const float* ln2b = (const float*)d_in[20];

    const int M = BB * SS;                 // 4096 rows
    const size_t MB = 1048576;
    char* wsb = (char*)d_ws;
    ushort* Wq_bf = (ushort*)(wsb + 0 * MB);
    ushort* Wk_bf = (ushort*)(wsb + 8 * MB);
    ushort* Wv_bf = (ushort*)(wsb + 16 * MB);
    ushort* Wo_bf = (ushort*)(wsb + 24 * MB);
    ushort* W1_bf = (ushort*)(wsb + 32 * MB);
    ushort* W2_bf = (ushort*)(wsb + 40 * MB);
    ushort* qi_bf = (ushort*)(wsb + 48 * MB);
    ushort* ki_bf = (ushort*)(wsb + 56 * MB);
    ushort* vi_bf = (ushort*)(wsb + 64 * MB);
    ushort* Qb    = (ushort*)(wsb + 72 * MB);
    ushort* Kb    = (ushort*)(wsb + 80 * MB);
    ushort* Vb    = (ushort*)(wsb + 88 * MB);
    ushort* ATTb  = (ushort*)(wsb + 96 * MB);
    float*  Ysp0  = (float*)(wsb + 104 * MB);   // split-K partial 0 (16 MiB)
    float*  Ysp1  = (float*)(wsb + 120 * MB);   // split-K partial 1 (16 MiB)
    float*  xf    = (float*)(wsb + 48 * MB);    // alias qi/ki (dead after QKV)
    ushort* x_bf  = (ushort*)(wsb + 64 * MB);   // alias vi (dead after QKV)
    ushort* hidden= (ushort*)(wsb + 72 * MB);   // alias Q/K/V/ATT (dead)

    dim3 blk(256);

    // batch convert fp32 -> bf16: q/k/v inputs + all weights
    const unsigned int N4M = 4u * 1024 * 1024, N1M = 1024 * 1024;
    CvtArgs ca;
    ca.s[0] = query; ca.s[1] = key; ca.s[2] = values;
    ca.s[3] = Wq; ca.s[4] = Wk; ca.s[5] = Wv;
    ca.s[6] = Wo; ca.s[7] = W1; ca.s[8] = W2;
    ca.d[0] = qi_bf; ca.d[1] = ki_bf; ca.d[2] = vi_bf;
    ca.d[3] = Wq_bf; ca.d[4] = Wk_bf; ca.d[5] = Wv_bf;
    ca.d[6] = Wo_bf; ca.d[7] = W1_bf; ca.d[8] = W2_bf;
    ca.n[0] = N4M; ca.n[1] = N4M; ca.n[2] = N4M;
    ca.n[3] = N1M; ca.n[4] = N1M; ca.n[5] = N1M;
    ca.n[6] = N1M; ca.n[7] = N4M; ca.n[8] = N4M;
    convert_bf<<<dim3(2048, 9), blk, 0, stream>>>(ca);

    // QKV projections -> bf16: one z-batched dispatch, bf16 A via GLD16
    QkvArgs qa;
    qa.A[0] = qi_bf; qa.A[1] = ki_bf; qa.A[2] = vi_bf;
    qa.B[0] = Wq_bf; qa.B[1] = Wk_bf; qa.B[2] = Wv_bf;
    qa.bias[0] = bq; qa.bias[1] = bk; qa.bias[2] = bv;
    qa.C[0] = Qb; qa.C[1] = Kb; qa.C[2] = Vb;
    gemm_qkv<<<dim3(8, 32, 3), blk, 0, stream>>>(qa);

    // attention (flash-style, bf16 in/out)
    attn_flash<<<dim3(BB * HH * 16), blk, 0, stream>>>(Qb, Kb, Vb, gammas, maskp, ATTb);

    // output projection, split-K=2 (N=1024, K=1024): partials -> Ysp0/Ysp1
    {
        SkArgs s; s.A = ATTb; s.Bm = Wo_bf; s.C0 = Ysp0; s.C1 = Ysp1;
        s.lda = DDIM; s.Klen = DDIM / 2;
        gemm_splitk<<<dim3(8, 32, 2), blk, 0, stream>>>(s);
    }

    // x = LN(query + Ysp0 + Ysp1 + bo) -> xf fp32 + x_bf
    add_ln<true><<<dim3(M), blk, 0, stream>>>(query, Ysp0, Ysp1, bo, ln1w, ln1b, xf, x_bf);

    // hidden = relu(x @ W1^T + b1) -> bf16 (verified r8 config)
    gemm_bf<128, ushort, true><<<dim3(32, 32), blk, 0, stream>>>(x_bf, W1_bf, b1, hidden, DFFF, DDIM);

    // y = hidden @ W2^T, split-K=2 (N=1024, K=4096): partials -> Ysp0/Ysp1
    {
        SkArgs s; s.A = hidden; s.Bm = W2_bf; s.C0 = Ysp0; s.C1 = Ysp1;
        s.lda = DFFF; s.Klen = DFFF / 2;
        gemm_splitk<<<dim3(8, 32, 2), blk, 0, stream>>>(s);
    }

    // out = LN(x + Ysp0 + Ysp1 + b2) -> d_out (fp32)
    add_ln<false><<<dim3(M), blk, 0, stream>>>(xf, Ysp0, Ysp1, b2, ln2w, ln2b, (float*)d_out, nullptr);
}